// Round 9
// baseline (418.784 us; speedup 1.0000x reference)
//
#include <hip/hip_runtime.h>
#include <math.h>

#define NB 2
#define NL 2048
#define ND 512
#define NH 8
#define NDK 64
#define NROW (NB*NL)
#define HEADSZ (NB*NH*NL*NDK)
#define SEG_BIG ((size_t)NROW*ND)        // 2097152
#define SEG_SMALL ((size_t)ND*ND)        // 262144
#define TOT_CVT (6*SEG_BIG + 8*SEG_SMALL)

typedef __attribute__((ext_vector_type(8))) short bf16x8;
typedef __attribute__((ext_vector_type(4))) float f32x4;
typedef __attribute__((ext_vector_type(4))) short short4v;

// static device scratch
__device__ __align__(16) short g_bfin[TOT_CVT];                  // bf16 inputs: q,k,v (r,i) then 8 weights
__device__ __align__(16) short g_bq_r[HEADSZ], g_bq_i[HEADSZ];   // Q * 0.125, bf16 [b,h,l,d]
__device__ __align__(16) short g_bk_r[HEADSZ], g_bk_i[HEADSZ];   // K bf16 [b,h,l,d], cols PRE-SWIZZLED (g^=l&7)
__device__ __align__(16) short g_bv_r[HEADSZ], g_bv_i[HEADSZ];   // V^T bf16 [b,h,d,l]
__device__ __align__(16) short g_bo_r[SEG_BIG], g_bo_i[SEG_BIG]; // attn out bf16 [b*L+l][h*64+d]
__device__ float g_x_r[SEG_BIG];                                 // post-FC + residual (fp32)
__device__ float g_x_i[SEG_BIG];

static __device__ __forceinline__ short f2bf(float x) {
    unsigned u = __float_as_uint(x);
    u += 0x7FFFu + ((u >> 16) & 1u);   // RNE
    return (short)(u >> 16);
}
static __device__ __forceinline__ bf16x8 negbf(bf16x8 v) {
    #pragma unroll
    for (int e = 0; e < 8; ++e) v[e] ^= (short)0x8000;
    return v;
}

// ---------------- fp32 -> bf16 conversion pre-pass ----------------
struct SrcPtrs { const float* p[14]; };

__global__ __launch_bounds__(256)
void tobf(SrcPtrs sp)
{
    const size_t i = ((size_t)blockIdx.x*256 + threadIdx.x) * 8;
    if (i >= TOT_CVT) return;
    int seg; size_t off;
    if (i < 6*SEG_BIG) { seg = (int)(i / SEG_BIG); off = i % SEG_BIG; }
    else { const size_t j = i - 6*SEG_BIG; seg = 6 + (int)(j / SEG_SMALL); off = j % SEG_SMALL; }
    const float* s = sp.p[seg] + off;
    const float4 a = *(const float4*)(s);
    const float4 b = *(const float4*)(s + 4);
    bf16x8 o;
    o[0] = f2bf(a.x); o[1] = f2bf(a.y); o[2] = f2bf(a.z); o[3] = f2bf(a.w);
    o[4] = f2bf(b.x); o[5] = f2bf(b.y); o[6] = f2bf(b.z); o[7] = f2bf(b.w);
    *(bf16x8*)(g_bfin + i) = o;
}

// ---------------- bf16 MFMA complex GEMM ----------------
// Y[m][n] = sum_k X[m][k] * W[n][k]   (torch Linear: x @ W^T)
// MODE 0: which = blockIdx.z (0=Q scaled,1=K pre-swizzled,2=V^T)
// MODE 1: FC — X = g_bo planes, epilogue -> g_x fp32 with residual added
template<int MODE>
__global__ __launch_bounds__(256, 2)
void bgemm(const float* __restrict__ Rr, const float* __restrict__ Ri)
{
    __shared__ __align__(16) short sAr[64][64], sAi[64][64];
    __shared__ __align__(16) short sBr[64][64], sBi[64][64];

    const int bm = blockIdx.x, bn = blockIdx.y;
    const int which = (MODE == 0) ? blockIdx.z : 3;
    const int tx = threadIdx.x;
    const int wave = tx >> 6, lane = tx & 63;
    const int l15 = lane & 15, l4 = lane >> 4;

    const short* Xr = (MODE == 0) ? g_bfin + (size_t)(2*which)*SEG_BIG   : g_bo_r;
    const short* Xi = (MODE == 0) ? g_bfin + (size_t)(2*which+1)*SEG_BIG : g_bo_i;
    const short* Wr = g_bfin + 6*SEG_BIG + (size_t)(2*which)*SEG_SMALL;
    const short* Wi = g_bfin + 6*SEG_BIG + (size_t)(2*which+1)*SEG_SMALL;

    const int t0r = tx >> 3;      // staging row 0..31 (and +32)
    const int t0g = tx & 7;       // 8-elem group

    f32x4 Cr[4] = {}, Ci[4] = {};

    for (int kk = 0; kk < ND; kk += 64) {
        uint4 va0, va1, va2, va3, vb0, vb1, vb2, vb3;
        {
            const size_t a0 = (size_t)(bm*64 + t0r)*ND + kk + t0g*8;
            const size_t a1 = (size_t)(bm*64 + t0r + 32)*ND + kk + t0g*8;
            va0 = *(const uint4*)(Xr + a0); va1 = *(const uint4*)(Xi + a0);
            va2 = *(const uint4*)(Xr + a1); va3 = *(const uint4*)(Xi + a1);
            const size_t b0 = (size_t)(bn*64 + t0r)*ND + kk + t0g*8;
            const size_t b1 = (size_t)(bn*64 + t0r + 32)*ND + kk + t0g*8;
            vb0 = *(const uint4*)(Wr + b0); vb1 = *(const uint4*)(Wi + b0);
            vb2 = *(const uint4*)(Wr + b1); vb3 = *(const uint4*)(Wi + b1);
        }
        __syncthreads();
        {
            const int g0 = (t0g ^ (t0r & 7)) << 3;
            const int g1 = (t0g ^ ((t0r + 32) & 7)) << 3;
            *(uint4*)&sAr[t0r][g0]    = va0;
            *(uint4*)&sAi[t0r][g0]    = va1;
            *(uint4*)&sAr[t0r+32][g1] = va2;
            *(uint4*)&sAi[t0r+32][g1] = va3;
            *(uint4*)&sBr[t0r][g0]    = vb0;
            *(uint4*)&sBi[t0r][g0]    = vb1;
            *(uint4*)&sBr[t0r+32][g1] = vb2;
            *(uint4*)&sBi[t0r+32][g1] = vb3;
        }
        __syncthreads();

        #pragma unroll
        for (int ks = 0; ks < 2; ++ks) {
            const int arow = 16*wave + l15;
            const int ag = ((ks*4 + l4) ^ (arow & 7)) << 3;
            const bf16x8 aAr = *(const bf16x8*)&sAr[arow][ag];
            const bf16x8 aAi = *(const bf16x8*)&sAi[arow][ag];
            const bf16x8 aAn = negbf(aAi);
            #pragma unroll
            for (int nt = 0; nt < 4; ++nt) {
                const int brow = nt*16 + l15;
                const int bg = ((ks*4 + l4) ^ (brow & 7)) << 3;
                const bf16x8 bBr = *(const bf16x8*)&sBr[brow][bg];
                const bf16x8 bBi = *(const bf16x8*)&sBi[brow][bg];
                Cr[nt] = __builtin_amdgcn_mfma_f32_16x16x32_bf16(aAr, bBr, Cr[nt], 0, 0, 0);
                Cr[nt] = __builtin_amdgcn_mfma_f32_16x16x32_bf16(aAn, bBi, Cr[nt], 0, 0, 0);
                Ci[nt] = __builtin_amdgcn_mfma_f32_16x16x32_bf16(aAr, bBi, Ci[nt], 0, 0, 0);
                Ci[nt] = __builtin_amdgcn_mfma_f32_16x16x32_bf16(aAi, bBr, Ci[nt], 0, 0, 0);
            }
        }
    }

    // ---- epilogues ----
    const int m0 = bm*64 + 16*wave + 4*l4;    // 4 consecutive m in acc regs
    if (MODE == 0) {
        if (which == 2) {
            // V^T: [bb][head=bn][d][l], 4 consecutive l per store
            const int bb = m0 >> 11, ll = m0 & (NL-1);
            #pragma unroll
            for (int nt = 0; nt < 4; ++nt) {
                const int d = nt*16 + l15;
                short4v pr, pi;
                #pragma unroll
                for (int r = 0; r < 4; ++r) { pr[r] = f2bf(Cr[nt][r]); pi[r] = f2bf(Ci[nt][r]); }
                const size_t base = ((size_t)(bb*NH + bn)*NDK + d)*NL + ll;
                *(short4v*)(g_bv_r + base) = pr;
                *(short4v*)(g_bv_i + base) = pi;
            }
        } else {
            const float s = (which == 0) ? 0.125f : 1.0f;    // fold 1/sqrt(DK) into Q
            short* Pr = (which == 0) ? g_bq_r : g_bk_r;
            short* Pi = (which == 0) ? g_bq_i : g_bk_i;
            #pragma unroll
            for (int r = 0; r < 4; ++r) {
                const int m = m0 + r;
                const int bb = m >> 11, ll = m & (NL-1);
                const size_t base = ((size_t)(bb*NH + bn)*NL + ll)*NDK;
                #pragma unroll
                for (int nt = 0; nt < 4; ++nt) {
                    int col = nt*16 + l15;
                    if (which == 1)   // pre-swizzle K columns for linear DMA staging
                        col = (col & 7) | ((((col >> 3) ^ (ll & 7))) << 3);
                    Pr[base + col] = f2bf(Cr[nt][r]*s);
                    Pi[base + col] = f2bf(Ci[nt][r]*s);
                }
            }
        }
    } else {
        #pragma unroll
        for (int r = 0; r < 4; ++r) {
            const int m = m0 + r;
            const size_t base = (size_t)m*ND + bn*64;
            #pragma unroll
            for (int nt = 0; nt < 4; ++nt) {
                const size_t idx = base + nt*16 + l15;
                g_x_r[idx] = Cr[nt][r] + Rr[idx];
                g_x_i[idx] = Ci[nt][r] + Ri[idx];
            }
        }
    }
}

// ---------------- MFMA flash attention with CVSoftMax ----------------
// grid 512 (XCD-swizzled: each XCD owns 2 (b,h) pairs). 4 waves; wave w owns
// q-rows 16w..16w+15 of its q0 tile. K staged via global_load_lds DMA
// (pre-swizzled global layout), dbuf 32KB. V PREFETCHED into registers at
// chunk start (16 bf16x8) so PV is pure-register MFMA. Coef LDS 16KB.
// LDS 48KB. One barrier per chunk.
__global__ __launch_bounds__(256, 3)
void cattn()
{
    __shared__ __align__(16) short sK[2][8192];               // [buf][Kr 64x64 | Ki 64x64]
    __shared__ __align__(16) short sCr[64][64], sCi[64][64];  // coeffs [q][k] (own-wave region)

    // XCD swizzle: xcd = bid&7 owns (b,h) in {2*xcd, 2*xcd+1}
    const int nb = blockIdx.x;
    const int xcd = nb & 7, rest = nb >> 3;
    const int bh = xcd*2 + (rest >> 5);
    const int q0 = (rest & 31) * 64;
    const int b = bh >> 3, h = bh & 7;

    const int tx = threadIdx.x;
    const int wave = tx >> 6, lane = tx & 63;
    const int l15 = lane & 15, l4 = lane >> 4;

    const short* Kr = g_bk_r + (size_t)bh*NL*NDK;
    const short* Ki = g_bk_i + (size_t)bh*NL*NDK;
    const short* Vr = g_bv_r + (size_t)bh*NDK*NL;
    const short* Vi = g_bv_i + (size_t)bh*NDK*NL;

    bf16x8 aQr[2], aQi[2], aQn[2];
    {
        const size_t qb = ((size_t)bh*NL + q0 + 16*wave + l15)*NDK + 8*l4;
        aQr[0] = *(const bf16x8*)(g_bq_r + qb);
        aQr[1] = *(const bf16x8*)(g_bq_r + qb + 32);
        aQi[0] = *(const bf16x8*)(g_bq_i + qb);
        aQi[1] = *(const bf16x8*)(g_bq_i + qb + 32);
        aQn[0] = negbf(aQi[0]); aQn[1] = negbf(aQi[1]);
    }

    f32x4 Or[4] = {}, Oi[4] = {};
    float ws[4] = {0.f, 0.f, 0.f, 0.f};

    // per-wave DMA split: waves 0,1 -> Kr half; waves 2,3 -> Ki half.
    const short* kplane = (wave < 2) ? Kr : Ki;
    const int pofs = (wave >> 1) * 4096;     // LDS short offset of this plane
    const int ub   = (wave & 1) * 256;       // 16B-unit base within plane

    #define STAGE_K(CHUNK, BUF) do {                                          \
        const size_t gb_ = (size_t)(CHUNK) * 4096;                            \
        _Pragma("unroll")                                                     \
        for (int i_ = 0; i_ < 4; ++i_) {                                      \
            const int u_ = ub + i_*64;                                        \
            __builtin_amdgcn_global_load_lds(                                 \
                (const __attribute__((address_space(1))) void*)               \
                    (kplane + gb_ + (size_t)(u_ + lane)*8),                   \
                (__attribute__((address_space(3))) void*)                     \
                    &sK[BUF][pofs + u_*8], 16, 0, 0);                         \
        }                                                                     \
    } while (0)

    // prologue: stage chunk 0 into buf 0
    STAGE_K(0, 0);
    asm volatile("s_waitcnt vmcnt(0)" ::: "memory");
    __syncthreads();

    const float LOG2E = 1.44269504f;
    const float SHIFT = -4.0f*1.44269504f;

    for (int t = 0; t < 32; ++t) {
        const int cur = t & 1, nxt = cur ^ 1;
        const int c0 = t * 64;
        if (t < 31) STAGE_K(t + 1, nxt);   // buf[nxt] free since end of t-1

        // ---- V prefetch: issue all 16 fragment loads NOW; latency hides
        // under QK + softmax (first use is in PV, after sched_barrier).
        bf16x8 pVr[4][2], pVi[4][2];
        #pragma unroll
        for (int tt = 0; tt < 4; ++tt) {
            const size_t vb = (size_t)(tt*16 + l15)*NL + c0;
            #pragma unroll
            for (int c = 0; c < 2; ++c) {
                const int off = (c*4 + l4) << 3;
                pVr[tt][c] = *(const bf16x8*)(Vr + vb + off);
                pVi[tt][c] = *(const bf16x8*)(Vi + vb + off);
            }
        }

        // ---- QK^T tile-by-tile, coefficients emitted immediately ----
        #pragma unroll
        for (int tt = 0; tt < 4; ++tt) {
            const int row = tt*16 + l15;
            const int swb = row & 7;
            f32x4 Sr = {}, Si = {};
            #pragma unroll
            for (int c = 0; c < 2; ++c) {
                const int off = (((c*4 + l4) ^ swb) << 3);
                const bf16x8 bKr = *(const bf16x8*)&sK[cur][row*64 + off];
                const bf16x8 bKi = *(const bf16x8*)&sK[cur][4096 + row*64 + off];
                Sr = __builtin_amdgcn_mfma_f32_16x16x32_bf16(aQr[c], bKr, Sr, 0, 0, 0);
                Sr = __builtin_amdgcn_mfma_f32_16x16x32_bf16(aQn[c], bKi, Sr, 0, 0, 0);
                Si = __builtin_amdgcn_mfma_f32_16x16x32_bf16(aQr[c], bKi, Si, 0, 0, 0);
                Si = __builtin_amdgcn_mfma_f32_16x16x32_bf16(aQi[c], bKr, Si, 0, 0, 0);
            }
            #pragma unroll
            for (int r = 0; r < 4; ++r) {
                const int qrow = 16*wave + 4*l4 + r;
                const float s2 = fmaxf(fmaf(Sr[r], Sr[r], Si[r]*Si[r]), 1e-30f);
                const float irs = __builtin_amdgcn_rsqf(s2);   // 1/|s|
                const float mag = s2 * irs;                    // |s|
                const float w = exp2f(fmaf(mag, LOG2E, SHIFT));
                const float sc = w * irs;
                ws[r] += w;
                const int col = (row & 7) | ((((row >> 3) ^ (qrow & 7))) << 3);
                sCr[qrow][col] = f2bf(Sr[r]*sc);
                sCi[qrow][col] = f2bf(Si[r]*sc);
            }
        }

        // coef region is own-wave-only — wave-local LDS ordering suffices.
        asm volatile("s_waitcnt lgkmcnt(0)" ::: "memory");
        __builtin_amdgcn_sched_barrier(0);

        // ---- PV: coef A-frags from LDS, V B-frags already in registers ----
        bf16x8 aCr[2], aCi[2], aCn[2];
        {
            const int qrow = 16*wave + l15;
            const int swb = qrow & 7;
            #pragma unroll
            for (int c = 0; c < 2; ++c) {
                const int off = (((c*4 + l4) ^ swb) << 3);
                aCr[c] = *(const bf16x8*)&sCr[qrow][off];
                aCi[c] = *(const bf16x8*)&sCi[qrow][off];
                aCn[c] = negbf(aCi[c]);
            }
        }
        #pragma unroll
        for (int tt = 0; tt < 4; ++tt) {
            #pragma unroll
            for (int c = 0; c < 2; ++c) {
                Or[tt] = __builtin_amdgcn_mfma_f32_16x16x32_bf16(aCr[c], pVr[tt][c], Or[tt], 0, 0, 0);
                Or[tt] = __builtin_amdgcn_mfma_f32_16x16x32_bf16(aCn[c], pVi[tt][c], Or[tt], 0, 0, 0);
                Oi[tt] = __builtin_amdgcn_mfma_f32_16x16x32_bf16(aCr[c], pVi[tt][c], Oi[tt], 0, 0, 0);
                Oi[tt] = __builtin_amdgcn_mfma_f32_16x16x32_bf16(aCi[c], pVr[tt][c], Oi[tt], 0, 0, 0);
            }
        }

        asm volatile("s_waitcnt vmcnt(0)" ::: "memory");   // my K-DMA done
        __syncthreads();                                    // everyone's DMA done
    }

    // ---- epilogue: reduce ws across the 16-lane group, normalize, store ----
    #pragma unroll
    for (int r = 0; r < 4; ++r) {
        #pragma unroll
        for (int off = 8; off; off >>= 1) ws[r] += __shfl_xor(ws[r], off);
    }
    float inv[4];
    #pragma unroll
    for (int r = 0; r < 4; ++r) inv[r] = 1.0f / ws[r];
    #pragma unroll
    for (int t = 0; t < 4; ++t) {
        const int d = t*16 + l15;
        #pragma unroll
        for (int r = 0; r < 4; ++r) {
            const int q = q0 + 16*wave + 4*l4 + r;
            const size_t idx = ((size_t)b*NL + q)*ND + h*NDK + d;
            g_bo_r[idx] = f2bf(Or[t][r]*inv[r]);
            g_bo_i[idx] = f2bf(Oi[t][r]*inv[r]);
        }
    }
    #undef STAGE_K
}

// ---------------- covariance-whitening complex LayerNorm ----------------
__global__ __launch_bounds__(256)
void cvln(const float* __restrict__ ln_w, const float* __restrict__ lnb_r,
          const float* __restrict__ lnb_i, float2* __restrict__ out)
{
    __shared__ float red[4][5];
    const int row = blockIdx.x, tx = threadIdx.x;
    const float* xr = g_x_r + (size_t)row*ND;
    const float* xi = g_x_i + (size_t)row*ND;
    const float a0 = xr[tx], a1 = xr[tx+256];
    const float b0 = xi[tx], b1 = xi[tx+256];
    float s_r = a0 + a1, s_i = b0 + b1;
    float srr = a0*a0 + a1*a1, sii = b0*b0 + b1*b1, sri = a0*b0 + a1*b1;
    #pragma unroll
    for (int off = 32; off; off >>= 1) {
        s_r += __shfl_xor(s_r, off);  s_i += __shfl_xor(s_i, off);
        srr += __shfl_xor(srr, off);  sii += __shfl_xor(sii, off);
        sri += __shfl_xor(sri, off);
    }
    const int wave = tx >> 6, lane = tx & 63;
    if (lane == 0) { red[wave][0]=s_r; red[wave][1]=s_i; red[wave][2]=srr; red[wave][3]=sii; red[wave][4]=sri; }
    __syncthreads();
    s_r = red[0][0]+red[1][0]+red[2][0]+red[3][0];
    s_i = red[0][1]+red[1][1]+red[2][1]+red[3][1];
    srr = red[0][2]+red[1][2]+red[2][2]+red[3][2];
    sii = red[0][3]+red[1][3]+red[2][3]+red[3][3];
    sri = red[0][4]+red[1][4]+red[2][4]+red[3][4];

    const float invD = 1.0f/ND;
    const float mr = s_r*invD, mi = s_i*invD;
    const float vrr = srr*invD - mr*mr + 1e-6f;
    const float vii = sii*invD - mi*mi + 1e-6f;
    const float vri = sri*invD - mr*mi;
    const float s  = sqrtf(vrr*vii - vri*vri);
    const float t  = sqrtf(vrr + vii + 2.0f*s);
    const float inv = 1.0f/(s*t);
    const float rrr = (vii + s)*inv, rii = (vrr + s)*inv, rri = -vri*inv;

    #pragma unroll
    for (int p = 0; p < 2; ++p) {
        const int d = tx + p*256;
        const float cxr = (p ? a1 : a0) - mr;
        const float cxi = (p ? b1 : b0) - mi;
        const float yr = rrr*cxr + rri*cxi;
        const float yi = rri*cxr + rii*cxi;
        const float w00 = ln_w[d], w01 = ln_w[512 + d];
        const float w10 = ln_w[1024 + d], w11 = ln_w[1536 + d];
        out[(size_t)row*ND + d] = make_float2(w00*yr + w01*yi + lnb_r[d],
                                              w10*yr + w11*yi + lnb_i[d]);
    }
}

extern "C" void kernel_launch(void* const* d_in, const int* in_sizes, int n_in,
                              void* d_out, int out_size, void* d_ws, size_t ws_size,
                              hipStream_t stream)
{
    (void)in_sizes; (void)n_in; (void)d_ws; (void)ws_size; (void)out_size;
    const float* q_r  = (const float*)d_in[0];
    const float* q_i  = (const float*)d_in[1];
    const float* ln_w = (const float*)d_in[14];
    const float* lnbr = (const float*)d_in[15];
    const float* lnbi = (const float*)d_in[16];

    SrcPtrs sp;
    // order matches g_bfin segments: q_r,q_i,k_r,k_i,v_r,v_i, wq_r,wq_i,wk_r,wk_i,wv_r,wv_i,fc_r,fc_i
    for (int j = 0; j < 14; ++j) sp.p[j] = (const float*)d_in[j];

    const int cvt_blocks = (int)((TOT_CVT/8 + 255)/256);
    tobf<<<cvt_blocks, 256, 0, stream>>>(sp);
    bgemm<0><<<dim3(NROW/64, ND/64, 3), 256, 0, stream>>>(nullptr, nullptr);
    cattn<<<512, 256, 0, stream>>>();
    bgemm<1><<<dim3(NROW/64, ND/64), 256, 0, stream>>>(q_r, q_i);
    cvln<<<NROW, 256, 0, stream>>>(ln_w, lnbr, lnbi, (float2*)d_out);
}

// Round 10
// 176.456 us; speedup vs baseline: 2.3733x; 2.3733x over previous
//
#include <hip/hip_runtime.h>
#include <math.h>

#define NB 2
#define NL 2048
#define ND 512
#define NH 8
#define NDK 64
#define NROW (NB*NL)
#define HEADSZ (NB*NH*NL*NDK)
#define SEG_BIG ((size_t)NROW*ND)        // 2097152
#define SEG_SMALL ((size_t)ND*ND)        // 262144
#define TOT_CVT (6*SEG_BIG + 8*SEG_SMALL)

typedef __attribute__((ext_vector_type(8))) short bf16x8;
typedef __attribute__((ext_vector_type(4))) float f32x4;
typedef __attribute__((ext_vector_type(4))) short short4v;

// static device scratch
__device__ __align__(16) short g_bfin[TOT_CVT];                  // bf16 inputs: q,k,v (r,i) then 8 weights
__device__ __align__(16) short g_bq_r[HEADSZ], g_bq_i[HEADSZ];   // Q * 0.125, bf16 [b,h,l,d]
__device__ __align__(16) short g_bk_r[HEADSZ], g_bk_i[HEADSZ];   // K bf16 [b,h,l,d], d-groups PRE-SWIZZLED (g^=l&7)
__device__ __align__(16) short g_bv_r[HEADSZ], g_bv_i[HEADSZ];   // V^T bf16 [b,h,d,l], l-groups PRE-SWIZZLED (g^=d&7)
__device__ __align__(16) short g_bo_r[SEG_BIG], g_bo_i[SEG_BIG]; // attn out bf16 [b*L+l][h*64+d]
__device__ float g_x_r[SEG_BIG];                                 // post-FC + residual (fp32)
__device__ float g_x_i[SEG_BIG];

static __device__ __forceinline__ short f2bf(float x) {
    unsigned u = __float_as_uint(x);
    u += 0x7FFFu + ((u >> 16) & 1u);   // RNE
    return (short)(u >> 16);
}
static __device__ __forceinline__ bf16x8 negbf(bf16x8 v) {
    #pragma unroll
    for (int e = 0; e < 8; ++e) v[e] ^= (short)0x8000;
    return v;
}

// ---------------- fp32 -> bf16 conversion pre-pass ----------------
struct SrcPtrs { const float* p[14]; };

__global__ __launch_bounds__(256)
void tobf(SrcPtrs sp)
{
    const size_t i = ((size_t)blockIdx.x*256 + threadIdx.x) * 8;
    if (i >= TOT_CVT) return;
    int seg; size_t off;
    if (i < 6*SEG_BIG) { seg = (int)(i / SEG_BIG); off = i % SEG_BIG; }
    else { const size_t j = i - 6*SEG_BIG; seg = 6 + (int)(j / SEG_SMALL); off = j % SEG_SMALL; }
    const float* s = sp.p[seg] + off;
    const float4 a = *(const float4*)(s);
    const float4 b = *(const float4*)(s + 4);
    bf16x8 o;
    o[0] = f2bf(a.x); o[1] = f2bf(a.y); o[2] = f2bf(a.z); o[3] = f2bf(a.w);
    o[4] = f2bf(b.x); o[5] = f2bf(b.y); o[6] = f2bf(b.z); o[7] = f2bf(b.w);
    *(bf16x8*)(g_bfin + i) = o;
}

// ---------------- bf16 MFMA complex GEMM ----------------
// Y[m][n] = sum_k X[m][k] * W[n][k]   (torch Linear: x @ W^T)
// MODE 0: which = blockIdx.z (0=Q scaled, 1=K pre-swizzled, 2=V^T pre-swizzled)
// MODE 1: FC — X = g_bo planes, epilogue -> g_x fp32 with residual added
template<int MODE>
__global__ __launch_bounds__(256, 2)
void bgemm(const float* __restrict__ Rr, const float* __restrict__ Ri)
{
    __shared__ __align__(16) short sAr[64][64], sAi[64][64];
    __shared__ __align__(16) short sBr[64][64], sBi[64][64];

    const int bm = blockIdx.x, bn = blockIdx.y;
    const int which = (MODE == 0) ? blockIdx.z : 3;
    const int tx = threadIdx.x;
    const int wave = tx >> 6, lane = tx & 63;
    const int l15 = lane & 15, l4 = lane >> 4;

    const short* Xr = (MODE == 0) ? g_bfin + (size_t)(2*which)*SEG_BIG   : g_bo_r;
    const short* Xi = (MODE == 0) ? g_bfin + (size_t)(2*which+1)*SEG_BIG : g_bo_i;
    const short* Wr = g_bfin + 6*SEG_BIG + (size_t)(2*which)*SEG_SMALL;
    const short* Wi = g_bfin + 6*SEG_BIG + (size_t)(2*which+1)*SEG_SMALL;

    const int t0r = tx >> 3;      // staging row 0..31 (and +32)
    const int t0g = tx & 7;       // 8-elem group

    f32x4 Cr[4] = {}, Ci[4] = {};

    for (int kk = 0; kk < ND; kk += 64) {
        uint4 va0, va1, va2, va3, vb0, vb1, vb2, vb3;
        {
            const size_t a0 = (size_t)(bm*64 + t0r)*ND + kk + t0g*8;
            const size_t a1 = (size_t)(bm*64 + t0r + 32)*ND + kk + t0g*8;
            va0 = *(const uint4*)(Xr + a0); va1 = *(const uint4*)(Xi + a0);
            va2 = *(const uint4*)(Xr + a1); va3 = *(const uint4*)(Xi + a1);
            const size_t b0 = (size_t)(bn*64 + t0r)*ND + kk + t0g*8;
            const size_t b1 = (size_t)(bn*64 + t0r + 32)*ND + kk + t0g*8;
            vb0 = *(const uint4*)(Wr + b0); vb1 = *(const uint4*)(Wi + b0);
            vb2 = *(const uint4*)(Wr + b1); vb3 = *(const uint4*)(Wi + b1);
        }
        __syncthreads();
        {
            const int g0 = (t0g ^ (t0r & 7)) << 3;
            const int g1 = (t0g ^ ((t0r + 32) & 7)) << 3;
            *(uint4*)&sAr[t0r][g0]    = va0;
            *(uint4*)&sAi[t0r][g0]    = va1;
            *(uint4*)&sAr[t0r+32][g1] = va2;
            *(uint4*)&sAi[t0r+32][g1] = va3;
            *(uint4*)&sBr[t0r][g0]    = vb0;
            *(uint4*)&sBi[t0r][g0]    = vb1;
            *(uint4*)&sBr[t0r+32][g1] = vb2;
            *(uint4*)&sBi[t0r+32][g1] = vb3;
        }
        __syncthreads();

        #pragma unroll
        for (int ks = 0; ks < 2; ++ks) {
            const int arow = 16*wave + l15;
            const int ag = ((ks*4 + l4) ^ (arow & 7)) << 3;
            const bf16x8 aAr = *(const bf16x8*)&sAr[arow][ag];
            const bf16x8 aAi = *(const bf16x8*)&sAi[arow][ag];
            const bf16x8 aAn = negbf(aAi);
            #pragma unroll
            for (int nt = 0; nt < 4; ++nt) {
                const int brow = nt*16 + l15;
                const int bg = ((ks*4 + l4) ^ (brow & 7)) << 3;
                const bf16x8 bBr = *(const bf16x8*)&sBr[brow][bg];
                const bf16x8 bBi = *(const bf16x8*)&sBi[brow][bg];
                Cr[nt] = __builtin_amdgcn_mfma_f32_16x16x32_bf16(aAr, bBr, Cr[nt], 0, 0, 0);
                Cr[nt] = __builtin_amdgcn_mfma_f32_16x16x32_bf16(aAn, bBi, Cr[nt], 0, 0, 0);
                Ci[nt] = __builtin_amdgcn_mfma_f32_16x16x32_bf16(aAr, bBi, Ci[nt], 0, 0, 0);
                Ci[nt] = __builtin_amdgcn_mfma_f32_16x16x32_bf16(aAi, bBr, Ci[nt], 0, 0, 0);
            }
        }
    }

    // ---- epilogues ----
    const int m0 = bm*64 + 16*wave + 4*l4;    // 4 consecutive m in acc regs
    if (MODE == 0) {
        if (which == 2) {
            // V^T: [bb][head=bn][d][l], PRE-SWIZZLED l-groups within each
            // 64-l chunk: l' = chunkbase | ((lgrp ^ (d&7))<<3) | (l&7).
            // 4 consecutive l per store stay in one group (ll%4==0).
            const int bb = m0 >> 11, ll = m0 & (NL-1);
            #pragma unroll
            for (int nt = 0; nt < 4; ++nt) {
                const int d = nt*16 + l15;
                short4v pr, pi;
                #pragma unroll
                for (int r = 0; r < 4; ++r) { pr[r] = f2bf(Cr[nt][r]); pi[r] = f2bf(Ci[nt][r]); }
                const int lswz = (ll & ~63) | (((((ll >> 3) & 7) ^ (d & 7))) << 3) | (ll & 7);
                const size_t base = ((size_t)(bb*NH + bn)*NDK + d)*NL + lswz;
                *(short4v*)(g_bv_r + base) = pr;
                *(short4v*)(g_bv_i + base) = pi;
            }
        } else {
            const float s = (which == 0) ? 0.125f : 1.0f;    // fold 1/sqrt(DK) into Q
            short* Pr = (which == 0) ? g_bq_r : g_bk_r;
            short* Pi = (which == 0) ? g_bq_i : g_bk_i;
            #pragma unroll
            for (int r = 0; r < 4; ++r) {
                const int m = m0 + r;
                const int bb = m >> 11, ll = m & (NL-1);
                const size_t base = ((size_t)(bb*NH + bn)*NL + ll)*NDK;
                #pragma unroll
                for (int nt = 0; nt < 4; ++nt) {
                    int col = nt*16 + l15;
                    if (which == 1)   // pre-swizzle K d-groups for linear DMA staging
                        col = (col & 7) | ((((col >> 3) ^ (ll & 7))) << 3);
                    Pr[base + col] = f2bf(Cr[nt][r]*s);
                    Pi[base + col] = f2bf(Ci[nt][r]*s);
                }
            }
        }
    } else {
        #pragma unroll
        for (int r = 0; r < 4; ++r) {
            const int m = m0 + r;
            const size_t base = (size_t)m*ND + bn*64;
            #pragma unroll
            for (int nt = 0; nt < 4; ++nt) {
                const size_t idx = base + nt*16 + l15;
                g_x_r[idx] = Cr[nt][r] + Rr[idx];
                g_x_i[idx] = Ci[nt][r] + Ri[idx];
            }
        }
    }
}

// ---------------- MFMA flash attention with CVSoftMax ----------------
// grid 512 (XCD-swizzled). 4 waves; wave w owns q-rows 16w..16w+15.
// BOTH K and V staged via global_load_lds DMA (pre-swizzled global layouts),
// double-buffered: K+V 64KB + coef 16KB = 80KB LDS. Each wave DMAs one plane
// (Kr/Ki/Vr/Vi, 8x16B per lane). One barrier per chunk; all mid-chunk waits
// are LDS-latency only.
__global__ __launch_bounds__(256, 2)
void cattn()
{
    __shared__ __align__(16) short sKV[2][16384];             // [buf][Kr|Ki|Vr|Vi] 4096 shorts each
    __shared__ __align__(16) short sCr[64][64], sCi[64][64];  // coeffs [q][k] (own-wave region)

    // XCD swizzle: xcd = bid&7 owns (b,h) in {2*xcd, 2*xcd+1}
    const int nb = blockIdx.x;
    const int xcd = nb & 7, rest = nb >> 3;
    const int bh = xcd*2 + (rest >> 5);
    const int q0 = (rest & 31) * 64;
    const int b = bh >> 3, h = bh & 7;

    const int tx = threadIdx.x;
    const int wave = tx >> 6, lane = tx & 63;
    const int l15 = lane & 15, l4 = lane >> 4;

    const short* Kr = g_bk_r + (size_t)bh*NL*NDK;
    const short* Ki = g_bk_i + (size_t)bh*NL*NDK;
    const short* Vr = g_bv_r + (size_t)bh*NDK*NL;
    const short* Vi = g_bv_i + (size_t)bh*NDK*NL;

    bf16x8 aQr[2], aQi[2], aQn[2];
    {
        const size_t qb = ((size_t)bh*NL + q0 + 16*wave + l15)*NDK + 8*l4;
        aQr[0] = *(const bf16x8*)(g_bq_r + qb);
        aQr[1] = *(const bf16x8*)(g_bq_r + qb + 32);
        aQi[0] = *(const bf16x8*)(g_bq_i + qb);
        aQi[1] = *(const bf16x8*)(g_bq_i + qb + 32);
        aQn[0] = negbf(aQi[0]); aQn[1] = negbf(aQi[1]);
    }

    f32x4 Or[4] = {}, Oi[4] = {};
    float ws[4] = {0.f, 0.f, 0.f, 0.f};

    // per-wave DMA plane: 0=Kr 1=Ki 2=Vr 3=Vi. 8 x 16B per lane per chunk.
    const short* kvplane = (wave == 0) ? Kr : (wave == 1) ? Ki : (wave == 2) ? Vr : Vi;
    const bool isV = wave >= 2;
    const int pbase = wave * 4096;           // LDS short offset of this plane

    // K plane source rows are contiguous (chunk*4096 linear); V plane source
    // is strided: unit u -> d = u>>3 (row), g = u&7 (16B group), src =
    // d*NL + c0 + g*8 (global pre-swizzled so linear LDS == swizzled layout).
    #define STAGE_KV(CHUNK, BUF) do {                                         \
        _Pragma("unroll")                                                     \
        for (int i_ = 0; i_ < 8; ++i_) {                                      \
            const int u_ = i_*64 + lane;                                      \
            const size_t src_ = isV                                           \
                ? (size_t)(u_ >> 3)*NL + (CHUNK)*64 + (u_ & 7)*8              \
                : (size_t)(CHUNK)*4096 + (size_t)u_*8;                        \
            __builtin_amdgcn_global_load_lds(                                 \
                (const __attribute__((address_space(1))) void*)               \
                    (kvplane + src_),                                         \
                (__attribute__((address_space(3))) void*)                     \
                    &sKV[BUF][pbase + u_*8], 16, 0, 0);                       \
        }                                                                     \
    } while (0)

    // prologue: stage chunk 0 into buf 0
    STAGE_KV(0, 0);
    asm volatile("s_waitcnt vmcnt(0)" ::: "memory");
    __syncthreads();

    const float LOG2E = 1.44269504f;
    const float SHIFT = -4.0f*1.44269504f;

    for (int t = 0; t < 32; ++t) {
        const int cur = t & 1, nxt = cur ^ 1;
        if (t < 31) STAGE_KV(t + 1, nxt);   // buf[nxt] free since end of t-1

        // ---- QK^T tile-by-tile, coefficients emitted immediately ----
        #pragma unroll
        for (int tt = 0; tt < 4; ++tt) {
            const int row = tt*16 + l15;
            const int swb = row & 7;
            f32x4 Sr = {}, Si = {};
            __builtin_amdgcn_s_setprio(1);
            #pragma unroll
            for (int c = 0; c < 2; ++c) {
                const int off = (((c*4 + l4) ^ swb) << 3);
                const bf16x8 bKr = *(const bf16x8*)&sKV[cur][row*64 + off];
                const bf16x8 bKi = *(const bf16x8*)&sKV[cur][4096 + row*64 + off];
                Sr = __builtin_amdgcn_mfma_f32_16x16x32_bf16(aQr[c], bKr, Sr, 0, 0, 0);
                Sr = __builtin_amdgcn_mfma_f32_16x16x32_bf16(aQn[c], bKi, Sr, 0, 0, 0);
                Si = __builtin_amdgcn_mfma_f32_16x16x32_bf16(aQr[c], bKi, Si, 0, 0, 0);
                Si = __builtin_amdgcn_mfma_f32_16x16x32_bf16(aQi[c], bKr, Si, 0, 0, 0);
            }
            __builtin_amdgcn_s_setprio(0);
            #pragma unroll
            for (int r = 0; r < 4; ++r) {
                const int qrow = 16*wave + 4*l4 + r;
                const float s2 = fmaxf(fmaf(Sr[r], Sr[r], Si[r]*Si[r]), 1e-30f);
                const float irs = __builtin_amdgcn_rsqf(s2);   // 1/|s|
                const float mag = s2 * irs;                    // |s|
                const float w = exp2f(fmaf(mag, LOG2E, SHIFT));
                const float sc = w * irs;
                ws[r] += w;
                const int col = (row & 7) | ((((row >> 3) ^ (qrow & 7))) << 3);
                sCr[qrow][col] = f2bf(Sr[r]*sc);
                sCi[qrow][col] = f2bf(Si[r]*sc);
            }
        }

        // coef region is own-wave-only — wave-local LDS ordering suffices.
        asm volatile("s_waitcnt lgkmcnt(0)" ::: "memory");
        __builtin_amdgcn_sched_barrier(0);

        // ---- PV: coef A-frags + V B-frags, all from LDS ----
        bf16x8 aCr[2], aCi[2], aCn[2];
        {
            const int qrow = 16*wave + l15;
            const int swb = qrow & 7;
            #pragma unroll
            for (int c = 0; c < 2; ++c) {
                const int off = (((c*4 + l4) ^ swb) << 3);
                aCr[c] = *(const bf16x8*)&sCr[qrow][off];
                aCi[c] = *(const bf16x8*)&sCi[qrow][off];
                aCn[c] = negbf(aCi[c]);
            }
        }
        #pragma unroll
        for (int tt = 0; tt < 4; ++tt) {
            const int vrow = tt*16 + l15;
            const int swb = vrow & 7;
            #pragma unroll
            for (int c = 0; c < 2; ++c) {
                const int off = (((c*4 + l4) ^ swb) << 3);
                const bf16x8 bVr = *(const bf16x8*)&sKV[cur][8192  + vrow*64 + off];
                const bf16x8 bVi = *(const bf16x8*)&sKV[cur][12288 + vrow*64 + off];
                Or[tt] = __builtin_amdgcn_mfma_f32_16x16x32_bf16(aCr[c], bVr, Or[tt], 0, 0, 0);
                Or[tt] = __builtin_amdgcn_mfma_f32_16x16x32_bf16(aCn[c], bVi, Or[tt], 0, 0, 0);
                Oi[tt] = __builtin_amdgcn_mfma_f32_16x16x32_bf16(aCr[c], bVi, Oi[tt], 0, 0, 0);
                Oi[tt] = __builtin_amdgcn_mfma_f32_16x16x32_bf16(aCi[c], bVr, Oi[tt], 0, 0, 0);
            }
        }

        asm volatile("s_waitcnt vmcnt(0)" ::: "memory");   // my KV-DMA done
        __syncthreads();                                    // everyone's DMA done
    }

    // ---- epilogue: reduce ws across the 16-lane group, normalize, store ----
    #pragma unroll
    for (int r = 0; r < 4; ++r) {
        #pragma unroll
        for (int off = 8; off; off >>= 1) ws[r] += __shfl_xor(ws[r], off);
    }
    float inv[4];
    #pragma unroll
    for (int r = 0; r < 4; ++r) inv[r] = 1.0f / ws[r];
    #pragma unroll
    for (int t = 0; t < 4; ++t) {
        const int d = t*16 + l15;
        #pragma unroll
        for (int r = 0; r < 4; ++r) {
            const int q = q0 + 16*wave + 4*l4 + r;
            const size_t idx = ((size_t)b*NL + q)*ND + h*NDK + d;
            g_bo_r[idx] = f2bf(Or[t][r]*inv[r]);
            g_bo_i[idx] = f2bf(Oi[t][r]*inv[r]);
        }
    }
    #undef STAGE_KV
}

// ---------------- covariance-whitening complex LayerNorm ----------------
__global__ __launch_bounds__(256)
void cvln(const float* __restrict__ ln_w, const float* __restrict__ lnb_r,
          const float* __restrict__ lnb_i, float2* __restrict__ out)
{
    __shared__ float red[4][5];
    const int row = blockIdx.x, tx = threadIdx.x;
    const float* xr = g_x_r + (size_t)row*ND;
    const float* xi = g_x_i + (size_t)row*ND;
    const float a0 = xr[tx], a1 = xr[tx+256];
    const float b0 = xi[tx], b1 = xi[tx+256];
    float s_r = a0 + a1, s_i = b0 + b1;
    float srr = a0*a0 + a1*a1, sii = b0*b0 + b1*b1, sri = a0*b0 + a1*b1;
    #pragma unroll
    for (int off = 32; off; off >>= 1) {
        s_r += __shfl_xor(s_r, off);  s_i += __shfl_xor(s_i, off);
        srr += __shfl_xor(srr, off);  sii += __shfl_xor(sii, off);
        sri += __shfl_xor(sri, off);
    }
    const int wave = tx >> 6, lane = tx & 63;
    if (lane == 0) { red[wave][0]=s_r; red[wave][1]=s_i; red[wave][2]=srr; red[wave][3]=sii; red[wave][4]=sri; }
    __syncthreads();
    s_r = red[0][0]+red[1][0]+red[2][0]+red[3][0];
    s_i = red[0][1]+red[1][1]+red[2][1]+red[3][1];
    srr = red[0][2]+red[1][2]+red[2][2]+red[3][2];
    sii = red[0][3]+red[1][3]+red[2][3]+red[3][3];
    sri = red[0][4]+red[1][4]+red[2][4]+red[3][4];

    const float invD = 1.0f/ND;
    const float mr = s_r*invD, mi = s_i*invD;
    const float vrr = srr*invD - mr*mr + 1e-6f;
    const float vii = sii*invD - mi*mi + 1e-6f;
    const float vri = sri*invD - mr*mi;
    const float s  = sqrtf(vrr*vii - vri*vri);
    const float t  = sqrtf(vrr + vii + 2.0f*s);
    const float inv = 1.0f/(s*t);
    const float rrr = (vii + s)*inv, rii = (vrr + s)*inv, rri = -vri*inv;

    #pragma unroll
    for (int p = 0; p < 2; ++p) {
        const int d = tx + p*256;
        const float cxr = (p ? a1 : a0) - mr;
        const float cxi = (p ? b1 : b0) - mi;
        const float yr = rrr*cxr + rri*cxi;
        const float yi = rri*cxr + rii*cxi;
        const float w00 = ln_w[d], w01 = ln_w[512 + d];
        const float w10 = ln_w[1024 + d], w11 = ln_w[1536 + d];
        out[(size_t)row*ND + d] = make_float2(w00*yr + w01*yi + lnb_r[d],
                                              w10*yr + w11*yi + lnb_i[d]);
    }
}

extern "C" void kernel_launch(void* const* d_in, const int* in_sizes, int n_in,
                              void* d_out, int out_size, void* d_ws, size_t ws_size,
                              hipStream_t stream)
{
    (void)in_sizes; (void)n_in; (void)d_ws; (void)ws_size; (void)out_size;
    const float* q_r  = (const float*)d_in[0];
    const float* q_i  = (const float*)d_in[1];
    const float* ln_w = (const float*)d_in[14];
    const float* lnbr = (const float*)d_in[15];
    const float* lnbi = (const float*)d_in[16];

    SrcPtrs sp;
    // order matches g_bfin segments: q_r,q_i,k_r,k_i,v_r,v_i, wq_r,wq_i,wk_r,wk_i,wv_r,wv_i,fc_r,fc_i
    for (int j = 0; j < 14; ++j) sp.p[j] = (const float*)d_in[j];

    const int cvt_blocks = (int)((TOT_CVT/8 + 255)/256);
    tobf<<<cvt_blocks, 256, 0, stream>>>(sp);
    bgemm<0><<<dim3(NROW/64, ND/64, 3), 256, 0, stream>>>(nullptr, nullptr);
    cattn<<<512, 256, 0, stream>>>();
    bgemm<1><<<dim3(NROW/64, ND/64), 256, 0, stream>>>(q_r, q_i);
    cvln<<<NROW, 256, 0, stream>>>(ln_w, lnbr, lnbi, (float2*)d_out);
}